// Round 8
// baseline (215.084 us; speedup 1.0000x reference)
//
#include <hip/hip_runtime.h>
#include <hip/hip_bf16.h>
#include <stdint.h>

// WeightOnlyPerChannelQuantizedLinear: out[b,n] = (sum_k x[b,k]*w[n,k]) * scale[n]
// x: fp32 [16][8192], w: int8-valued int32 [28672][8192], scale: fp32 [28672]
//
// R8: six designs converge at 4.4-4.9 TB/s weight-read BW; only visit size ever
// moved the needle (128B->2KB: +10%). This round: 2KB visits (WK=512), halved
// stream count (~8K chip-wide), no k-split/atomics/memset (full-K waves, direct
// store), R7's DMA + counted vmcnt + involution swizzle kept verbatim.

using f32x4 = __attribute__((ext_vector_type(4))) float;
using s16x8 = __attribute__((ext_vector_type(8))) short;
using i32x4 = __attribute__((ext_vector_type(4))) int;

static constexpr int K      = 8192;
static constexpr int N      = 28672;
static constexpr int NSTEPS = K / 32;       // 256 MFMA k-steps total
static constexpr int WK     = 512;          // ints per row per window (2 KB visits)
static constexpr int NWIN   = K / WK;       // 16 windows
static constexpr int SPW    = WK / 32;      // 16 MFMA steps per window

// ---------------------------------------------------------------------------
// Pre-pass (R1 mapping): lane l=(q<<4)|row of step kk holds A[row][kk*32+q*8+j],
// j=0..7, packed 4 dwords (even j low half), at afrag[kk*64 + l].
// ---------------------------------------------------------------------------
__global__ __launch_bounds__(256) void prep_a_kernel(const float* __restrict__ act,
                                                     uint4* __restrict__ afrag) {
  const int t   = blockIdx.x * 256 + threadIdx.x;
  const int kk  = t >> 6;
  const int l   = t & 63;
  const int row = l & 15;
  const int q   = l >> 4;
  const float* src = act + row * K + kk * 32 + q * 8;
  uint d[4];
#pragma unroll
  for (int p = 0; p < 4; ++p) {
    uint u0 = __builtin_bit_cast(uint, src[2 * p]);
    uint u1 = __builtin_bit_cast(uint, src[2 * p + 1]);
    u0 += 0x7fffu + ((u0 >> 16) & 1u);            // RNE f32 -> bf16
    u1 += 0x7fffu + ((u1 >> 16) & 1u);
    d[p] = (u0 >> 16) | (u1 & 0xffff0000u);
  }
  afrag[t] = make_uint4(d[0], d[1], d[2], d[3]);
}

__device__ __forceinline__ uint pack_bf16(int a, int b) {
  uint fa = __builtin_bit_cast(uint, (float)a);
  uint fb = __builtin_bit_cast(uint, (float)b);
  return (fa >> 16) | (fb & 0xffff0000u);   // exact for |w|<=127
}

// ---------------------------------------------------------------------------
// Main kernel. Grid N/16 = 1792, block = ONE wave. Wave owns 16 channels x
// full K. LDS = [2][16][512] int32 (64 KB, 2 blocks/CU). Per window m:
//   issue 16 afrag loads (m) -> issue 16 global_load_lds (m+1; 2 KB/row,
//   2 instrs... no: 1 row per DMA instr covers 16B*64 lanes = 1KB; WK=512 ints
//   = 2KB/row -> 2 DMA per row? No: 16 rows x 2KB = 32KB staged by 32 DMA of
//   1KB each; batch them as 32 loads) -> s_waitcnt vmcnt(32) -> 16 MFMA steps.
// Source-lane involution swizzle (R7-verified): LDS 16B-slot j of row r holds
// global chunk j ^ sperm(r), sperm(r)=((r&3)<<1)|((r>>2)&1); reads XOR back.
// Epilogue: scale + direct store (every (b,n) covered exactly once).
// ---------------------------------------------------------------------------
__global__ __launch_bounds__(64) void wq_linear_kernel(
    const int* __restrict__ wt,        // int32 [N][K]
    const uint4* __restrict__ afrag,   // [NSTEPS][64]
    const float* __restrict__ scaler,  // [N]
    float* __restrict__ out) {         // [16][N]
  __shared__ int buf[2][16 * WK];      // 64 KB
  const int l  = threadIdx.x;          // 0..63
  const int c  = l & 15;               // channel within tile (B col)
  const int q  = l >> 4;               // k-chunk selector
  const int n0 = blockIdx.x << 4;

  // stage window mm into buf[bi]: 2 DMA per row (1 KB each), linear LDS dest,
  // source 16B-chunk index = (h*64 + l) ^ sperm(r)  [chunk space: 128/row]
#define STAGE(mm, bi)                                                        \
  _Pragma("unroll") for (int r = 0; r < 16; ++r) {                           \
    const int sp = ((r & 3) << 1) | ((r >> 2) & 1);                          \
    _Pragma("unroll") for (int h = 0; h < 2; ++h) {                          \
      const int* gsrc = wt + (size_t)(n0 + r) * K + (mm) * WK                \
                        + ((((h << 6) + l) ^ sp) << 2);                      \
      __builtin_amdgcn_global_load_lds(                                      \
          (const __attribute__((address_space(1))) unsigned int*)gsrc,       \
          (__attribute__((address_space(3))) unsigned int*)                  \
              &buf[bi][r * WK + (h << 8)],                                   \
          16, 0, 0);                                                         \
    }                                                                        \
  }

  STAGE(0, 0)

  f32x4 acc = {0.f, 0.f, 0.f, 0.f};
  const int spc = ((c & 3) << 1) | ((c >> 2) & 1);   // sperm(c)

#pragma unroll 1
  for (int m = 0; m < NWIN; ++m) {
    // A-fragments for window m (L2-resident), FIFO-ordered before DMA(m+1)
    uint4 ag[SPW];
#pragma unroll
    for (int s = 0; s < SPW; ++s)
      ag[s] = afrag[(size_t)(m * SPW + s) * 64 + l];

    if (m + 1 < NWIN) {
      STAGE(m + 1, (m + 1) & 1)
      // outstanding: ag(m)[16] + DMA(m+1)[32]; DMA(m) retired before ag(m).
      asm volatile("s_waitcnt vmcnt(32)" ::: "memory");  // m+1 stays in flight
    } else {
      asm volatile("s_waitcnt vmcnt(0)" ::: "memory");   // tail drain
    }
    __builtin_amdgcn_sched_barrier(0);   // keep ds_reads below the wait

    const char* rowp = (const char*)&buf[m & 1][c * WK];
#pragma unroll
    for (int s = 0; s < SPW; ++s) {
      // logical 16B-chunk within row-window = s*8 + q*2 + h; physical ^= spc
      const int o0 = (s << 7) + ((((q << 1) | 0) ^ spc) << 4);
      const int o1 = (s << 7) + ((((q << 1) | 1) ^ spc) << 4);
      const i32x4 w0 = *(const i32x4*)(rowp + o0);   // k = s*32 + q*8 + 0..3
      const i32x4 w1 = *(const i32x4*)(rowp + o1);   // k = s*32 + q*8 + 4..7
      const uint b0 = pack_bf16(w0.x, w0.y);
      const uint b1 = pack_bf16(w0.z, w0.w);
      const uint b2 = pack_bf16(w1.x, w1.y);
      const uint b3 = pack_bf16(w1.z, w1.w);
      s16x8 a = __builtin_bit_cast(s16x8, ag[s]);
      s16x8 b = __builtin_bit_cast(s16x8, make_uint4(b0, b1, b2, b3));
      acc = __builtin_amdgcn_mfma_f32_16x16x32_bf16(a, b, acc, 0, 0, 0);
    }
  }

  // acc layout (m89-verified): col = c, row(batch) = q*4 + i. Direct store.
  const float scl = scaler[n0 + c];
#pragma unroll
  for (int i = 0; i < 4; ++i)
    out[(size_t)((q << 2) + i) * N + n0 + c] = acc[i] * scl;
#undef STAGE
}

extern "C" void kernel_launch(void* const* d_in, const int* in_sizes, int n_in,
                              void* d_out, int out_size, void* d_ws, size_t ws_size,
                              hipStream_t stream) {
  const float* act    = (const float*)d_in[0];
  const int*   wt     = (const int*)d_in[1];
  const float* scaler = (const float*)d_in[2];
  float*       out    = (float*)d_out;
  uint4*       afrag  = (uint4*)d_ws;   // 256 KB of A-fragments

  prep_a_kernel<<<(NSTEPS * 64) / 256, 256, 0, stream>>>(act, afrag);
  wq_linear_kernel<<<N / 16, 64, 0, stream>>>(wt, afrag, scaler, out);
}